// Round 1
// baseline (357.153 us; speedup 1.0000x reference)
//
#include <hip/hip_runtime.h>
#include <hip/hip_bf16.h>

#define NPTS   32768
#define EEDGES 1048576
#define PTSC   1024   // points per cloud
#define NCLOUD 32

// ---------------- encoder: pos[N,3] -> x[N,128], 3 tanh layers ----------------
// one wave handles 4 points; lane l owns row l of layer1/2 and rows l,l+64 of layer3.
__global__ __launch_bounds__(256) void enc_kernel(
    const float* __restrict__ pos,
    const float* __restrict__ w1, const float* __restrict__ b1,
    const float* __restrict__ w2, const float* __restrict__ b2,
    const float* __restrict__ w3, const float* __restrict__ b3,
    float* __restrict__ x) {
  int wid  = (blockIdx.x * blockDim.x + threadIdx.x) >> 6;
  int lane = threadIdx.x & 63;
  int i0 = wid * 4;
  if (i0 >= NPTS) return;

  float w1a = w1[lane * 3 + 0], w1b = w1[lane * 3 + 1], w1c = w1[lane * 3 + 2];
  float bb1 = b1[lane];

  float h1[4];
#pragma unroll
  for (int p = 0; p < 4; ++p) {
    int i = i0 + p;
    float px = pos[i * 3 + 0], py = pos[i * 3 + 1], pz = pos[i * 3 + 2];
    h1[p] = tanhf(w1a * px + w1b * py + w1c * pz + bb1);
  }

  float bb2 = b2[lane];
  float acc2[4] = {bb2, bb2, bb2, bb2};
  for (int k = 0; k < 64; ++k) {
    float w = w2[lane * 64 + k];
#pragma unroll
    for (int p = 0; p < 4; ++p) acc2[p] += w * __shfl(h1[p], k);
  }
  float h2[4];
#pragma unroll
  for (int p = 0; p < 4; ++p) h2[p] = tanhf(acc2[p]);

  float bb3a = b3[lane], bb3b = b3[lane + 64];
  float acc3a[4] = {bb3a, bb3a, bb3a, bb3a};
  float acc3b[4] = {bb3b, bb3b, bb3b, bb3b};
  for (int k = 0; k < 64; ++k) {
    float wa = w3[lane * 64 + k];
    float wb = w3[(lane + 64) * 64 + k];
#pragma unroll
    for (int p = 0; p < 4; ++p) {
      float h = __shfl(h2[p], k);
      acc3a[p] += wa * h;
      acc3b[p] += wb * h;
    }
  }
#pragma unroll
  for (int p = 0; p < 4; ++p) {
    int i = i0 + p;
    x[(size_t)i * 128 + lane]      = tanhf(acc3a[p]);
    x[(size_t)i * 128 + 64 + lane] = tanhf(acc3b[p]);
  }
}

// ---------------- edge binning ----------------
__global__ __launch_bounds__(256) void hist_kernel(const int* __restrict__ ei,
                                                   int* __restrict__ cnt) {
  int e = blockIdx.x * 256 + threadIdx.x;
  if (e >= EEDGES) return;
  int d = ei[EEDGES + e];
  atomicAdd(&cnt[d], 1);
}

__global__ __launch_bounds__(1024) void scan_kernel(const int* __restrict__ cnt,
                                                    int* __restrict__ binStart) {
  __shared__ int sums[1024];
  int t = threadIdx.x;
  int base = t * 32;
  int local[32];
  int s = 0;
#pragma unroll
  for (int k = 0; k < 32; ++k) { local[k] = cnt[base + k]; s += local[k]; }
  sums[t] = s;
  __syncthreads();
  for (int off = 1; off < 1024; off <<= 1) {
    int v = (t >= off) ? sums[t - off] : 0;
    __syncthreads();
    sums[t] += v;
    __syncthreads();
  }
  int excl = sums[t] - s;  // exclusive prefix of this thread's chunk
#pragma unroll
  for (int k = 0; k < 32; ++k) { binStart[base + k] = excl; excl += local[k]; }
  if (t == 1023) binStart[NPTS] = excl;
}

__global__ __launch_bounds__(256) void scatter_kernel(const int* __restrict__ ei,
                                                      const int* __restrict__ binStart,
                                                      int* __restrict__ cursor,
                                                      int* __restrict__ bins) {
  int e = blockIdx.x * 256 + threadIdx.x;
  if (e >= EEDGES) return;
  int s = ei[e];
  int d = ei[EEDGES + e];
  int p = atomicAdd(&cursor[d], 1);
  bins[binStart[d] + p] = s;
}

// ---------------- per-node aggregate -> per-cloud 131-dim sum ----------------
// block = 256 threads (4 waves); block handles 32 consecutive nodes (same cloud).
// wave w handles 8 nodes. lane owns x-dims 2l,2l+1; lanes 0..2 own pos dims.
__global__ __launch_bounds__(256) void agg_kernel(
    const float* __restrict__ x, const float* __restrict__ pos,
    const int* __restrict__ binStart, const int* __restrict__ cnt,
    const int* __restrict__ bins, float* __restrict__ Macc) {
  int w = threadIdx.x >> 6, lane = threadIdx.x & 63;
  int base = blockIdx.x * 32;

  float2 mx = make_float2(0.f, 0.f);
  float mp = 0.f;

  for (int t8 = 0; t8 < 8; ++t8) {
    int i = base + w * 8 + t8;
    int s0 = binStart[i];
    int n = cnt[i];
    float2 sx = make_float2(0.f, 0.f);
    float sp = 0.f;
    for (int c0 = 0; c0 < n; c0 += 64) {
      int mlen = min(n - c0, 64);
      int sv = (lane < mlen) ? bins[s0 + c0 + lane] : 0;
      for (int j = 0; j < mlen; ++j) {
        int s = __shfl(sv, j);
        const float2 v = *reinterpret_cast<const float2*>(x + (size_t)s * 128 + lane * 2);
        sx.x += v.x; sx.y += v.y;
        if (lane < 3) sp += pos[s * 3 + lane];
      }
    }
    // self loop (rel = 0)
    {
      const float2 v = *reinterpret_cast<const float2*>(x + (size_t)i * 128 + lane * 2);
      sx.x += v.x; sx.y += v.y;
    }
    float pi = (lane < 3) ? pos[i * 3 + lane] : 0.f;
    sp += pi;
    float inv = 1.f / (float)(n + 1);
    mx.x += sx.x * inv;
    mx.y += sx.y * inv;
    mp += sp * inv - pi;
  }

  __shared__ float part[4][132];
  part[w][lane * 2]     = mx.x;
  part[w][lane * 2 + 1] = mx.y;
  if (lane < 3) part[w][128 + lane] = mp;
  __syncthreads();

  int cloud = base >> 10;
  for (int d = threadIdx.x; d < 131; d += 256) {
    float v = part[0][d] + part[1][d] + part[2][d] + part[3][d];
    atomicAdd(&Macc[cloud * 131 + d], v);
  }
}

// ---------------- tail: local_nn+global_nn on pooled means + decoder ----------------
__global__ __launch_bounds__(256) void final_kernel(
    const float* __restrict__ Macc,
    const float* __restrict__ loc_w, const float* __restrict__ loc_b,
    const float* __restrict__ glob_w, const float* __restrict__ glob_b,
    const float* __restrict__ d1w, const float* __restrict__ d1b,
    const float* __restrict__ d2w, const float* __restrict__ d2b,
    const float* __restrict__ d3w, const float* __restrict__ d3b,
    float* __restrict__ out) {
  int c = blockIdx.x, t = threadIdx.x;
  __shared__ float m[131];
  __shared__ float tt[256];
  __shared__ float u[384];
  __shared__ float a[256];
  __shared__ float bv[128];

  if (t < 131) m[t] = Macc[c * 131 + t] * (1.0f / (float)PTSC);
  __syncthreads();

  {
    float acc = loc_b[t];
    for (int k = 0; k < 131; ++k) acc += loc_w[t * 131 + k] * m[k];
    tt[t] = acc;
  }
  __syncthreads();

  for (int j = t; j < 384; j += 256) {
    float acc = glob_b[j];
    for (int k = 0; k < 256; ++k) acc += glob_w[j * 256 + k] * tt[k];
    u[j] = acc;
  }
  __syncthreads();

  {
    float acc = d1b[t];
    for (int k = 0; k < 384; ++k) acc += d1w[t * 384 + k] * u[k];
    a[t] = tanhf(acc);
  }
  __syncthreads();

  if (t < 128) {
    float acc = d2b[t];
    for (int k = 0; k < 256; ++k) acc += d2w[t * 256 + k] * a[k];
    bv[t] = tanhf(acc);
  }
  __syncthreads();

  if (t < 16) {
    float acc = d3b[t];
    for (int k = 0; k < 128; ++k) acc += d3w[t * 128 + k] * bv[k];
    out[c * 16 + t] = acc;
  }
}

extern "C" void kernel_launch(void* const* d_in, const int* in_sizes, int n_in,
                              void* d_out, int out_size, void* d_ws, size_t ws_size,
                              hipStream_t stream) {
  const float* pos    = (const float*)d_in[0];
  const int*   ei     = (const int*)d_in[1];
  const float* enc1_w = (const float*)d_in[2];
  const float* enc1_b = (const float*)d_in[3];
  const float* enc2_w = (const float*)d_in[4];
  const float* enc2_b = (const float*)d_in[5];
  const float* enc3_w = (const float*)d_in[6];
  const float* enc3_b = (const float*)d_in[7];
  const float* loc_w  = (const float*)d_in[8];
  const float* loc_b  = (const float*)d_in[9];
  const float* glob_w = (const float*)d_in[10];
  const float* glob_b = (const float*)d_in[11];
  const float* d1w    = (const float*)d_in[12];
  const float* d1b    = (const float*)d_in[13];
  const float* d2w    = (const float*)d_in[14];
  const float* d2b    = (const float*)d_in[15];
  const float* d3w    = (const float*)d_in[16];
  const float* d3b    = (const float*)d_in[17];
  float* out = (float*)d_out;

  // workspace layout (bytes)
  char* ws = (char*)d_ws;
  float* x        = (float*)(ws + 0);                        // N*128 f32 = 16,777,216
  int*   cnt      = (int*)  (ws + 16777216);                 // N i32    =    131,072
  int*   binStart = (int*)  (ws + 16777216 + 131072);        // N+1 i32  (pad 131,328)
  int*   cursor   = (int*)  (ws + 16777216 + 131072 + 131328);
  int*   bins     = (int*)  (ws + 16777216 + 131072 + 131328 + 131072);   // E i32
  float* Macc     = (float*)(ws + 16777216 + 131072 + 131328 + 131072 + 4194304); // 32*131 f32

  hipMemsetAsync(cnt,    0, NPTS * sizeof(int), stream);
  hipMemsetAsync(cursor, 0, NPTS * sizeof(int), stream);
  hipMemsetAsync(Macc,   0, NCLOUD * 131 * sizeof(float), stream);

  enc_kernel<<<NPTS / 4 / 4, 256, 0, stream>>>(pos, enc1_w, enc1_b, enc2_w, enc2_b,
                                               enc3_w, enc3_b, x);
  hist_kernel<<<EEDGES / 256, 256, 0, stream>>>(ei, cnt);
  scan_kernel<<<1, 1024, 0, stream>>>(cnt, binStart);
  scatter_kernel<<<EEDGES / 256, 256, 0, stream>>>(ei, binStart, cursor, bins);
  agg_kernel<<<NPTS / 32, 256, 0, stream>>>(x, pos, binStart, cnt, bins, Macc);
  final_kernel<<<NCLOUD, 256, 0, stream>>>(Macc, loc_w, loc_b, glob_w, glob_b,
                                           d1w, d1b, d2w, d2b, d3w, d3b, out);
}